// Round 6
// baseline (96.942 us; speedup 1.0000x reference)
//
#include <hip/hip_runtime.h>

// Depth-4 path signature, D=6. Chunked Chen recursion + tensor-algebra
// combine tree. All per-lane state is NAMED SCALARS (R2-R4: private arrays
// stay in scratch; named scalars fixed it, 188->110us).
//
// R6: 3 launches (chunk P=1024; combine g=32 x2). Chunk: per-lane vi/vj via
// ds_read (replaces 2x 5-deep cndmask sel6), unroll-2 to kill pipeline moves.
// Combine: 3-deep prefetch sets (lookahead ~2 products, covers L2 latency).
//
// State layout (floats), padded stride 1600 (16B-aligned):
//   L4 [0,1296)  L3 [1296,1512)  L2 [1512,1548)  L1 [1548,1554)
// Final output uses reference layout: L1[0,6) L2[6,42) L3[42,258) L4[258,1554).
#define SIGSZ 1554
#define PSTRIDE 1600
#define OFF4 0
#define OFF3 1296
#define OFF2 1512
#define OFF1 1548
#define MAXROWS 100   // LDS row capacity in sig_chunk (chunk_len <= 99)

#define REP6(M) M(0) M(1) M(2) M(3) M(4) M(5)
#define REP6B(M, k) M(k, 0) M(k, 1) M(k, 2) M(k, 3) M(k, 4) M(k, 5)
#define REP36(M) \
  REP6B(M, 0) REP6B(M, 1) REP6B(M, 2) REP6B(M, 3) REP6B(M, 4) REP6B(M, 5)

__device__ __forceinline__ float sel6(int idx, float a0, float a1, float a2,
                                      float a3, float a4, float a5) {
  float r = a0;
  r = (idx == 1) ? a1 : r;
  r = (idx == 2) ? a2 : r;
  r = (idx == 3) ? a3 : r;
  r = (idx == 4) ? a4 : r;
  r = (idx == 5) ? a5 : r;
  return r;
}

// ---------------------------------------------------------------------------
// Phase 1: one 64-thread block per chunk; lane p<36 owns (i,j)=(p/6,p%6).
// S2[ij], S3[ij.], S4[ij..], S1[i] in named-scalar registers. x rows staged
// to LDS once; loop reads rows (broadcast b64) + per-lane x[t,i]/x[t,j]
// (b32), both prefetched 2 rows ahead.
//   S4[ijkl] += G*v_l,  G   = (vi*vj/24 + S1[i]*vj/6 + S2[ij]/2)*vk + S3[ijk]
//   S3[ijk]  += G2*vk,  G2  =  vi*vj/6  + S1[i]*vj/2 + S2[ij]
//   S2[ij]   += (vi/2 + S1[i])*vj ;  S1[i] += vi      (old values on RHS)
// ---------------------------------------------------------------------------
__global__ __launch_bounds__(64, 1) void sig_chunk(const float* __restrict__ x,
                                                   float* __restrict__ out,
                                                   int n_inc, int chunk_len) {
  __shared__ float xs[MAXROWS * 6];
  const int c = blockIdx.x;
  const int p = threadIdx.x;
  const int t0 = c * chunk_len;
  int t1 = t0 + chunk_len; if (t1 > n_inc) t1 = n_inc;
  const int steps = (t1 > t0) ? (t1 - t0) : 0;
  const int pc = (p < 36) ? p : 35;
  const int i = pc / 6, j = pc % 6;
  const bool act = (p < 36);

  // ---- stage rows t0..t0+steps (steps+1 rows) into LDS ----
  const int nfl = (steps > 0) ? (steps + 1) * 6 : 0;
  for (int idx = p; idx < nfl; idx += 64) xs[idx] = x[(size_t)t0 * 6 + idx];
  __syncthreads();

#define DECL_S4(k, l) float s4_##k##_##l = 0.f;
  REP36(DECL_S4)
#undef DECL_S4
#define DECL_S3(k) float s3_##k = 0.f;
  REP6(DECL_S3)
#undef DECL_S3
  float s1i = 0.f, s2 = 0.f;

  float cr0 = 0, cr1 = 0, cr2 = 0, cr3 = 0, cr4 = 0, cr5 = 0;
  float nr0 = 0, nr1 = 0, nr2 = 0, nr3 = 0, nr4 = 0, nr5 = 0;
  float xic = 0, xjc = 0, xin = 0, xjn = 0;
  if (steps > 0) {
    const float2* q0 = (const float2*)(xs);
    float2 a0 = q0[0], b0 = q0[1], d0 = q0[2];
    cr0 = a0.x; cr1 = a0.y; cr2 = b0.x; cr3 = b0.y; cr4 = d0.x; cr5 = d0.y;
    const float2* q1 = (const float2*)(xs + 6);
    float2 a1 = q1[0], b1 = q1[1], d1 = q1[2];
    nr0 = a1.x; nr1 = a1.y; nr2 = b1.x; nr3 = b1.y; nr4 = d1.x; nr5 = d1.y;
    xic = xs[i]; xjc = xs[j];
    xin = xs[6 + i]; xjn = xs[6 + j];
  }

#pragma unroll 2
  for (int r = 0; r < steps; ++r) {
    const float v0 = nr0 - cr0, v1 = nr1 - cr1, v2 = nr2 - cr2;
    const float v3 = nr3 - cr3, v4 = nr4 - cr4, v5 = nr5 - cr5;
    const float vi = xin - xic;
    const float vj = xjn - xjc;

    // branch-free LDS prefetch of row r+2 (clamped to last staged row)
    int ro = r + 2; ro = (ro > steps) ? steps : ro;
    const float2* qp = (const float2*)(xs + ro * 6);
    const float2 pa = qp[0], pb = qp[1], pd = qp[2];
    const float xi2 = xs[ro * 6 + i];
    const float xj2 = xs[ro * 6 + j];

    const float aa = vi * vj;
    const float sv = s1i * vj;
    const float G2  = fmaf(aa, 1.f / 6.f,  fmaf(sv, 0.5f,      s2));
    const float in4 = fmaf(aa, 1.f / 24.f, fmaf(sv, 1.f / 6.f, s2 * 0.5f));
#define MKG(k)                                    \
    const float G_##k = fmaf(in4, v##k, s3_##k);  \
    s3_##k = fmaf(G2, v##k, s3_##k);
    REP6(MKG)
#undef MKG
#define UPD4(k, l) s4_##k##_##l = fmaf(G_##k, v##l, s4_##k##_##l);
    REP36(UPD4)
#undef UPD4
    s2 = fmaf(fmaf(vi, 0.5f, s1i), vj, s2);   // old s1i
    s1i += vi;

    cr0 = nr0; cr1 = nr1; cr2 = nr2; cr3 = nr3; cr4 = nr4; cr5 = nr5;
    nr0 = pa.x; nr1 = pa.y; nr2 = pb.x; nr3 = pb.y; nr4 = pd.x; nr5 = pd.y;
    xic = xin; xjc = xjn; xin = xi2; xjn = xj2;
  }

  float* st = out + (size_t)c * PSTRIDE;
  if (act) {
    float4* o4 = (float4*)(st + OFF4 + pc * 36);
    float4 w;
    w.x = s4_0_0; w.y = s4_0_1; w.z = s4_0_2; w.w = s4_0_3; o4[0] = w;
    w.x = s4_0_4; w.y = s4_0_5; w.z = s4_1_0; w.w = s4_1_1; o4[1] = w;
    w.x = s4_1_2; w.y = s4_1_3; w.z = s4_1_4; w.w = s4_1_5; o4[2] = w;
    w.x = s4_2_0; w.y = s4_2_1; w.z = s4_2_2; w.w = s4_2_3; o4[3] = w;
    w.x = s4_2_4; w.y = s4_2_5; w.z = s4_3_0; w.w = s4_3_1; o4[4] = w;
    w.x = s4_3_2; w.y = s4_3_3; w.z = s4_3_4; w.w = s4_3_5; o4[5] = w;
    w.x = s4_4_0; w.y = s4_4_1; w.z = s4_4_2; w.w = s4_4_3; o4[6] = w;
    w.x = s4_4_4; w.y = s4_4_5; w.z = s4_5_0; w.w = s4_5_1; o4[7] = w;
    w.x = s4_5_2; w.y = s4_5_3; w.z = s4_5_4; w.w = s4_5_5; o4[8] = w;
#define ST3(k) st[OFF3 + pc * 6 + k] = s3_##k;
    REP6(ST3)
#undef ST3
    st[OFF2 + pc] = s2;
    if (j == 0) st[OFF1 + i] = s1i;
  }
}

// ---------------------------------------------------------------------------
// Phase 2: combine `group` consecutive states left-to-right. 256-thread
// blocks; lane t<216 owns triple (i,j,k) = (t/36, (t/6)%6, t%6), keeping
// C4[ijk,:] (6), C3[ijk], and REDUNDANT copies of C2[ij], C1[:] in regs.
// Lanes fully independent: B-slices loaded straight from global into named
// registers, rotating 3-deep prefetch (lookahead ~2 products). No LDS,
// no barriers.
//   C4[ijk,l] = A4 + B4[ijk,l] + A1[i]B3[jk,l] + A2[ij]B2[k,l] + A3[ijk]B1[l]
//   C3[ijk]   = A3 + B3[ijk] + A1[i]B2[jk] + A2[ij]B1[k]
//   C2[ij]    = A2 + B2[ij] + A1[i]B1[j] ;  C1 = A1 + B1   (old A on RHS)
// ---------------------------------------------------------------------------

// 31 named scalars per prefetch set
#define DECLSET(S)                                                  \
  float S##b4_0, S##b4_1, S##b4_2, S##b4_3, S##b4_4, S##b4_5;       \
  float S##b3r_0, S##b3r_1, S##b3r_2, S##b3r_3, S##b3r_4, S##b3r_5; \
  float S##b2r_0, S##b2r_1, S##b2r_2, S##b2r_3, S##b2r_4, S##b2r_5; \
  float S##b1_0, S##b1_1, S##b1_2, S##b1_3, S##b1_4, S##b1_5;       \
  float S##b2ij, S##b2jk, S##b3ijk, S##b1k, S##b1j;

#define LOADSET(S, bp) {                                            \
  const float2* q4 = (const float2*)((bp) + oB4);                   \
  float2 u0 = q4[0], u1 = q4[1], u2 = q4[2];                        \
  S##b4_0 = u0.x; S##b4_1 = u0.y; S##b4_2 = u1.x;                   \
  S##b4_3 = u1.y; S##b4_4 = u2.x; S##b4_5 = u2.y;                   \
  const float2* q3 = (const float2*)((bp) + oB3r);                  \
  float2 w0 = q3[0], w1 = q3[1], w2 = q3[2];                        \
  S##b3r_0 = w0.x; S##b3r_1 = w0.y; S##b3r_2 = w1.x;                \
  S##b3r_3 = w1.y; S##b3r_4 = w2.x; S##b3r_5 = w2.y;                \
  const float2* q2 = (const float2*)((bp) + oB2r);                  \
  float2 y0 = q2[0], y1 = q2[1], y2 = q2[2];                        \
  S##b2r_0 = y0.x; S##b2r_1 = y0.y; S##b2r_2 = y1.x;                \
  S##b2r_3 = y1.y; S##b2r_4 = y2.x; S##b2r_5 = y2.y;                \
  const float2* q1 = (const float2*)((bp) + OFF1);                  \
  float2 z0 = q1[0], z1 = q1[1], z2 = q1[2];                        \
  S##b1_0 = z0.x; S##b1_1 = z0.y; S##b1_2 = z1.x;                   \
  S##b1_3 = z1.y; S##b1_4 = z2.x; S##b1_5 = z2.y;                   \
  S##b2ij = (bp)[oB2ij]; S##b2jk = (bp)[oB2jk];                     \
  S##b3ijk = (bp)[oB3ijk];                                          \
  S##b1k = (bp)[oB1k]; S##b1j = (bp)[oB1j];                         \
}

#define PROD(S) {                                                   \
  const float a1i = sel6(i_, a1_0, a1_1, a1_2, a1_3, a1_4, a1_5);   \
  a4_0 = fmaf(a3, S##b1_0, fmaf(a2, S##b2r_0,                       \
         fmaf(a1i, S##b3r_0, a4_0 + S##b4_0)));                     \
  a4_1 = fmaf(a3, S##b1_1, fmaf(a2, S##b2r_1,                       \
         fmaf(a1i, S##b3r_1, a4_1 + S##b4_1)));                     \
  a4_2 = fmaf(a3, S##b1_2, fmaf(a2, S##b2r_2,                       \
         fmaf(a1i, S##b3r_2, a4_2 + S##b4_2)));                     \
  a4_3 = fmaf(a3, S##b1_3, fmaf(a2, S##b2r_3,                       \
         fmaf(a1i, S##b3r_3, a4_3 + S##b4_3)));                     \
  a4_4 = fmaf(a3, S##b1_4, fmaf(a2, S##b2r_4,                       \
         fmaf(a1i, S##b3r_4, a4_4 + S##b4_4)));                     \
  a4_5 = fmaf(a3, S##b1_5, fmaf(a2, S##b2r_5,                       \
         fmaf(a1i, S##b3r_5, a4_5 + S##b4_5)));                     \
  a3 = fmaf(a2, S##b1k, fmaf(a1i, S##b2jk, a3 + S##b3ijk));         \
  a2 = fmaf(a1i, S##b1j, a2 + S##b2ij);                             \
  a1_0 += S##b1_0; a1_1 += S##b1_1; a1_2 += S##b1_2;                \
  a1_3 += S##b1_3; a1_4 += S##b1_4; a1_5 += S##b1_5;                \
}

__global__ __launch_bounds__(256, 1) void sig_combine(const float* __restrict__ in,
                                                      float* __restrict__ out,
                                                      int n_total, int group,
                                                      int final_out) {
  const int b = blockIdx.x;
  const int p = threadIdx.x;
  const int start = b * group;
  int end = start + group; if (end > n_total) end = n_total;
  const int tc = (p < 216) ? p : 215;
  const bool act = (p < 216);
  const int k_ = tc % 6;
  const int ij = tc / 6;
  const int j_ = ij % 6;
  const int i_ = ij / 6;

  // loop-invariant element offsets
  const int oB4 = OFF4 + tc * 6;
  const int oB3r = OFF3 + (j_ * 6 + k_) * 6;
  const int oB2r = OFF2 + k_ * 6;
  const int oB2ij = OFF2 + ij;
  const int oB2jk = OFF2 + j_ * 6 + k_;
  const int oB3ijk = OFF3 + tc;
  const int oB1k = OFF1 + k_;
  const int oB1j = OFF1 + j_;

  // ---- init A from state `start` ----
  const float* sp0 = in + (size_t)start * PSTRIDE;
  float a4_0, a4_1, a4_2, a4_3, a4_4, a4_5;
  {
    const float2* q4 = (const float2*)(sp0 + oB4);
    float2 u0 = q4[0], u1 = q4[1], u2 = q4[2];
    a4_0 = u0.x; a4_1 = u0.y; a4_2 = u1.x;
    a4_3 = u1.y; a4_4 = u2.x; a4_5 = u2.y;
  }
  float a3 = sp0[oB3ijk];
  float a2 = sp0[oB2ij];
  float a1_0, a1_1, a1_2, a1_3, a1_4, a1_5;
  {
    const float2* q1 = (const float2*)(sp0 + OFF1);
    float2 z0 = q1[0], z1 = q1[1], z2 = q1[2];
    a1_0 = z0.x; a1_1 = z0.y; a1_2 = z1.x;
    a1_3 = z1.y; a1_4 = z2.x; a1_5 = z2.y;
  }

  DECLSET(A)
  DECLSET(B)
  DECLSET(C)

#define CL(sx) ((sx) < end ? (sx) : (end - 1))
  int s = start + 1;
  {
    LOADSET(A, in + (size_t)CL(s) * PSTRIDE)
    LOADSET(B, in + (size_t)CL(s + 1) * PSTRIDE)
    LOADSET(C, in + (size_t)CL(s + 2) * PSTRIDE)
  }
  while (s + 2 < end) {
    PROD(A)
    LOADSET(A, in + (size_t)CL(s + 3) * PSTRIDE)
    PROD(B)
    LOADSET(B, in + (size_t)CL(s + 4) * PSTRIDE)
    PROD(C)
    LOADSET(C, in + (size_t)CL(s + 5) * PSTRIDE)
    s += 3;
  }
  if (s < end) { PROD(A) }
  if (s + 1 < end) { PROD(B) }
#undef CL

  const float a1p = sel6(p, a1_0, a1_1, a1_2, a1_3, a1_4, a1_5);
  if (final_out) {
    float* o = out;   // reference layout: L1 0, L2 6, L3 42, L4 258
    if (act) {
      float2* o2 = (float2*)(o + 258 + tc * 6);
      float2 w;
      w.x = a4_0; w.y = a4_1; o2[0] = w;
      w.x = a4_2; w.y = a4_3; o2[1] = w;
      w.x = a4_4; w.y = a4_5; o2[2] = w;
      o[42 + tc] = a3;
      if (k_ == 0) o[6 + ij] = a2;
    }
    if (p < 6) o[p] = a1p;
  } else {
    float* st = out + (size_t)b * PSTRIDE;
    if (act) {
      float2* o2 = (float2*)(st + oB4);
      float2 w;
      w.x = a4_0; w.y = a4_1; o2[0] = w;
      w.x = a4_2; w.y = a4_3; o2[1] = w;
      w.x = a4_4; w.y = a4_5; o2[2] = w;
      st[oB3ijk] = a3;
      if (k_ == 0) st[oB2ij] = a2;
    }
    if (p < 6) st[OFF1 + p] = a1p;
  }
}

extern "C" void kernel_launch(void* const* d_in, const int* in_sizes, int n_in,
                              void* d_out, int out_size, void* d_ws, size_t ws_size,
                              hipStream_t stream) {
  const float* x = (const float*)d_in[0];
  const int Lrows = in_sizes[0] / 6;
  const int n_inc = Lrows - 1;

  int P = 1024;
  int chunk_len = (n_inc + P - 1) / P;
  if (chunk_len > MAXROWS - 1) {           // keep LDS staging in bounds
    chunk_len = MAXROWS - 1;
    P = (n_inc + chunk_len - 1) / chunk_len;
  }

  float* ws0 = (float*)d_ws;
  float* ws1 = ws0 + (size_t)P * PSTRIDE;

  sig_chunk<<<P, 64, 0, stream>>>(x, ws0, n_inc, chunk_len);

  float* cur = ws0;
  float* other = ws1;
  int n = P;
  while (n > 1) {
    const int g = (n <= 32) ? n : 32;
    const int nb = (n + g - 1) / g;
    const int fin = (nb == 1);
    sig_combine<<<nb, 256, 0, stream>>>(cur, fin ? (float*)d_out : other, n, g, fin);
    float* t = cur; cur = other; other = t;
    n = nb;
  }
}